// Round 1
// baseline (1554.894 us; speedup 1.0000x reference)
//
#include <hip/hip_runtime.h>

// GCN layer: out = segment_sum(edge_weight * (X@W)[edge_src], edge_dst) + bias
// X: [M,512] fp32, W: [512,128] fp32, bias: [128] fp32
// edges: src/dst int32 [E], weight fp32 [E]
// out: [M,128] fp32.  d_ws holds h = X@W ([M,128] fp32 = 51.2 MB).

#define D_IN  512
#define D_OUT 128

// ---------------- GEMM: h[M,128] = X[M,512] @ W[512,128] ----------------
// Block tile: 64 rows x 128 cols, BK = 64. 256 threads, each 4x8 outputs.
__global__ __launch_bounds__(256) void gemm_kernel(const float* __restrict__ X,
                                                   const float* __restrict__ W,
                                                   float* __restrict__ H, int M) {
    __shared__ float As[64][65];    // padded leading dim (bank conflicts)
    __shared__ float Bs[64][128];

    const int block_row = blockIdx.x * 64;
    const int tid = threadIdx.x;
    const int tx = tid % 16;        // col group: cols [tx*8, tx*8+8)
    const int ty = tid / 16;        // row group: rows [ty*4, ty*4+4)

    float acc[4][8];
#pragma unroll
    for (int r = 0; r < 4; r++)
#pragma unroll
        for (int c = 0; c < 8; c++) acc[r][c] = 0.f;

    for (int k0 = 0; k0 < D_IN; k0 += 64) {
        // A tile: 64 rows x 64 k = 1024 float4 slots; 256 threads x 4
#pragma unroll
        for (int i = 0; i < 4; i++) {
            int idx = tid + i * 256;       // float4 slot id
            int r   = idx / 16;            // row in tile
            int kq  = idx % 16;            // float4 index within 64 k
            int grow = block_row + r;
            float4 v = make_float4(0.f, 0.f, 0.f, 0.f);
            if (grow < M)
                v = *reinterpret_cast<const float4*>(&X[(size_t)grow * D_IN + k0 + kq * 4]);
            As[r][kq * 4 + 0] = v.x;
            As[r][kq * 4 + 1] = v.y;
            As[r][kq * 4 + 2] = v.z;
            As[r][kq * 4 + 3] = v.w;
        }
        // B tile: 64 k x 128 n = 2048 float4 slots; 256 threads x 8
#pragma unroll
        for (int i = 0; i < 8; i++) {
            int idx = tid + i * 256;
            int kk  = idx / 32;            // k row
            int nq  = idx % 32;            // float4 col
            float4 v = *reinterpret_cast<const float4*>(&W[(size_t)(k0 + kk) * D_OUT + nq * 4]);
            *reinterpret_cast<float4*>(&Bs[kk][nq * 4]) = v;
        }
        __syncthreads();

#pragma unroll
        for (int kk = 0; kk < 64; kk++) {
            float a[4];
            float b[8];
#pragma unroll
            for (int r = 0; r < 4; r++) a[r] = As[ty * 4 + r][kk];
            float4 b0 = *reinterpret_cast<const float4*>(&Bs[kk][tx * 8]);
            float4 b1 = *reinterpret_cast<const float4*>(&Bs[kk][tx * 8 + 4]);
            b[0] = b0.x; b[1] = b0.y; b[2] = b0.z; b[3] = b0.w;
            b[4] = b1.x; b[5] = b1.y; b[6] = b1.z; b[7] = b1.w;
#pragma unroll
            for (int r = 0; r < 4; r++)
#pragma unroll
                for (int c = 0; c < 8; c++)
                    acc[r][c] += a[r] * b[c];
        }
        __syncthreads();
    }

#pragma unroll
    for (int r = 0; r < 4; r++) {
        int grow = block_row + ty * 4 + r;
        if (grow < M) {
#pragma unroll
            for (int c = 0; c < 8; c += 4) {
                float4 v = make_float4(acc[r][c], acc[r][c + 1], acc[r][c + 2], acc[r][c + 3]);
                *reinterpret_cast<float4*>(&H[(size_t)grow * D_OUT + tx * 8 + c]) = v;
            }
        }
    }
}

// ---------------- init: out[i, :] = bias ----------------
__global__ __launch_bounds__(256) void init_kernel(float* __restrict__ out,
                                                   const float* __restrict__ bias,
                                                   long long n4) {
    long long gid = (long long)blockIdx.x * blockDim.x + threadIdx.x;  // float4 id
    if (gid >= n4) return;
    int col4 = (int)(gid & 31);     // 32 float4 per 128-col row
    float4 b = *reinterpret_cast<const float4*>(&bias[col4 * 4]);
    *reinterpret_cast<float4*>(&out[gid * 4]) = b;
}

// ---------------- scatter: out[dst] += w * h[src] ----------------
// 32 lanes per edge, each lane handles 4 consecutive cols (float4).
__global__ __launch_bounds__(256) void scatter_kernel(const float* __restrict__ H,
                                                      const int* __restrict__ src,
                                                      const int* __restrict__ dst,
                                                      const float* __restrict__ w,
                                                      float* __restrict__ out, int E) {
    long long gid = (long long)blockIdx.x * blockDim.x + threadIdx.x;
    long long e = gid >> 5;
    int lane = (int)(gid & 31);
    if (e >= E) return;
    int s = src[e];
    int d = dst[e];
    float wt = w[e];
    float4 v = *reinterpret_cast<const float4*>(&H[(size_t)s * D_OUT + lane * 4]);
    float* o = &out[(size_t)d * D_OUT + lane * 4];
    atomicAdd(o + 0, wt * v.x);
    atomicAdd(o + 1, wt * v.y);
    atomicAdd(o + 2, wt * v.z);
    atomicAdd(o + 3, wt * v.w);
}

extern "C" void kernel_launch(void* const* d_in, const int* in_sizes, int n_in,
                              void* d_out, int out_size, void* d_ws, size_t ws_size,
                              hipStream_t stream) {
    const float* features    = (const float*)d_in[0];
    const int*   edge_src    = (const int*)d_in[1];
    const int*   edge_dst    = (const int*)d_in[2];
    const float* edge_weight = (const float*)d_in[3];
    const float* weights     = (const float*)d_in[4];
    const float* bias        = (const float*)d_in[5];
    float* out = (float*)d_out;
    float* h   = (float*)d_ws;   // [M,128] fp32 scratch

    const int M = in_sizes[0] / D_IN;
    const int E = in_sizes[1];

    // 1) h = X @ W
    gemm_kernel<<<(M + 63) / 64, 256, 0, stream>>>(features, weights, h, M);

    // 2) out = bias (broadcast)
    long long n4 = (long long)M * D_OUT / 4;
    init_kernel<<<(int)((n4 + 255) / 256), 256, 0, stream>>>(out, bias, n4);

    // 3) out[dst] += w * h[src]
    long long nthreads = (long long)E * 32;
    scatter_kernel<<<(int)((nthreads + 255) / 256), 256, 0, stream>>>(
        h, edge_src, edge_dst, edge_weight, out, E);
}

// Round 2
// 495.551 us; speedup vs baseline: 3.1377x; 3.1377x over previous
//
#include <hip/hip_runtime.h>

// GCN layer: out = segment_sum(edge_weight * (X@W)[edge_src], edge_dst) + bias
// Round 2: (a) bf16 MFMA GEMM (16x16x32), h stored bf16
//          (b) atomic scatter replaced by CSR build + gather-aggregate
// ws layout (bytes):
//   hbf       [M*128 bf16]   @ 0          (25.6 MB)
//   Wt bf16   [128*512]      @ 25,600,000 (0.13 MB)  Wt[n][k]
//   deg  int  [M]            @ 25,731,072
//   rs   int  [M+1]          @ 26,131,072
//   cur  int  [M]            @ 26,531,088
//   csr  u64  [E]            @ 26,931,088 (5.12 MB)  (w_bits<<32 | src)
//   bsum int  [128]          @ 32,051,088
// total ~32.1 MB (round-1 proved ws >= 51.2 MB)

#define D_IN  512
#define D_OUT 128

typedef __attribute__((ext_vector_type(8))) short short8;
typedef __attribute__((ext_vector_type(4))) float f32x4;

static __device__ __forceinline__ unsigned short f2bf(float f) {
    unsigned u = __float_as_uint(f);
    unsigned r = (u + 0x7FFFu + ((u >> 16) & 1u)) >> 16;   // RNE
    return (unsigned short)r;
}

// ---- Wt[n][k] = bf16(W[k][n]) ----
__global__ __launch_bounds__(256) void wt_kernel(const float* __restrict__ W,
                                                 unsigned short* __restrict__ Wt) {
    int t = blockIdx.x * 256 + threadIdx.x;      // 65536 threads
    int n = t >> 9;          // /512
    int k = t & 511;
    Wt[t] = f2bf(W[(size_t)k * D_OUT + n]);
}

// ---- GEMM: hbf[M,128] = bf16(X[M,512] @ W) via MFMA 16x16x32 bf16 ----
// One wave -> 16 rows x 128 cols. Block = 4 waves. No LDS.
__global__ __launch_bounds__(256) void gemm_kernel(const float* __restrict__ X,
                                                   const unsigned short* __restrict__ Wt,
                                                   unsigned short* __restrict__ H, int M) {
    const int lane = threadIdx.x & 63;
    const int wave_id = blockIdx.x * 4 + (threadIdx.x >> 6);
    const int row0 = wave_id * 16;
    if (row0 >= M) return;

    const int m = lane & 15;      // A row / B col within tile
    const int q = lane >> 4;      // quad: k = q*8 + j

    f32x4 acc[8];
#pragma unroll
    for (int t = 0; t < 8; t++) acc[t] = (f32x4){0.f, 0.f, 0.f, 0.f};

    const float* xrow = X + (size_t)(row0 + m) * D_IN + q * 8;

    for (int kc = 0; kc < D_IN; kc += 32) {
        // A fragment: X[row0+m][kc + q*8 + j], j=0..7
        float4 u0 = *reinterpret_cast<const float4*>(xrow + kc);
        float4 u1 = *reinterpret_cast<const float4*>(xrow + kc + 4);
        short8 a;
        a[0] = (short)f2bf(u0.x); a[1] = (short)f2bf(u0.y);
        a[2] = (short)f2bf(u0.z); a[3] = (short)f2bf(u0.w);
        a[4] = (short)f2bf(u1.x); a[5] = (short)f2bf(u1.y);
        a[6] = (short)f2bf(u1.z); a[7] = (short)f2bf(u1.w);

#pragma unroll
        for (int t = 0; t < 8; t++) {
            // B fragment: W[kc+q*8+j][t*16+m] = Wt[(t*16+m)*512 + kc + q*8 + j]
            short8 b = *reinterpret_cast<const short8*>(
                Wt + (size_t)(t * 16 + m) * D_IN + kc + q * 8);
            acc[t] = __builtin_amdgcn_mfma_f32_16x16x32_bf16(a, b, acc[t], 0, 0, 0);
        }
    }

    // C layout: col = lane&15, row = q*4 + r
#pragma unroll
    for (int t = 0; t < 8; t++) {
#pragma unroll
        for (int r = 0; r < 4; r++) {
            H[(size_t)(row0 + q * 4 + r) * D_OUT + t * 16 + m] = f2bf(acc[t][r]);
        }
    }
}

// ---- zero deg ----
__global__ __launch_bounds__(256) void zero_kernel(int* __restrict__ deg, int M) {
    int i = blockIdx.x * 256 + threadIdx.x;
    if (i < M) deg[i] = 0;
}

// ---- histogram of dst ----
__global__ __launch_bounds__(256) void hist_kernel(const int* __restrict__ dst,
                                                   int* __restrict__ deg, int E) {
    int e = blockIdx.x * 256 + threadIdx.x;
    if (e < E) atomicAdd(&deg[dst[e]], 1);
}

// ---- scan pass 1: per-1024-chunk local exclusive scan + chunk totals ----
__global__ __launch_bounds__(256) void scan1_kernel(const int* __restrict__ deg,
                                                    int* __restrict__ rs,
                                                    int* __restrict__ bsum, int M) {
    __shared__ int sdata[256];
    const int tid = threadIdx.x;
    const int base = blockIdx.x * 1024 + tid * 4;
    int v[4];
#pragma unroll
    for (int i = 0; i < 4; i++) v[i] = (base + i < M) ? deg[base + i] : 0;
    int tsum = v[0] + v[1] + v[2] + v[3];
    sdata[tid] = tsum;
    __syncthreads();
    for (int off = 1; off < 256; off <<= 1) {
        int add = (tid >= off) ? sdata[tid - off] : 0;
        __syncthreads();
        sdata[tid] += add;
        __syncthreads();
    }
    int excl = sdata[tid] - tsum;
#pragma unroll
    for (int i = 0; i < 4; i++) {
        if (base + i < M) rs[base + i] = excl;
        excl += v[i];
    }
    if (tid == 255) bsum[blockIdx.x] = sdata[255];
}

// ---- scan pass 2: exclusive scan of chunk totals (<=128 chunks) ----
__global__ __launch_bounds__(128) void scan2_kernel(int* __restrict__ bsum, int NB) {
    __shared__ int sdata[128];
    const int tid = threadIdx.x;
    int v = (tid < NB) ? bsum[tid] : 0;
    sdata[tid] = v;
    __syncthreads();
    for (int off = 1; off < 128; off <<= 1) {
        int add = (tid >= off) ? sdata[tid - off] : 0;
        __syncthreads();
        sdata[tid] += add;
        __syncthreads();
    }
    if (tid < NB) bsum[tid] = sdata[tid] - v;
}

// ---- scan pass 3: apply chunk offsets; fill cursor; set rs[M]=E ----
__global__ __launch_bounds__(256) void scan3_kernel(int* __restrict__ rs,
                                                    int* __restrict__ cur,
                                                    const int* __restrict__ bsum,
                                                    int M, int E) {
    int i = blockIdx.x * 256 + threadIdx.x;
    if (i < M) {
        int val = rs[i] + bsum[i >> 10];
        rs[i] = val;
        cur[i] = val;
    }
    if (i == 0) rs[M] = E;
}

// ---- build CSR: csr[pos] = (w_bits<<32) | src ----
__global__ __launch_bounds__(256) void build_kernel(const int* __restrict__ src,
                                                    const int* __restrict__ dst,
                                                    const float* __restrict__ w,
                                                    int* __restrict__ cur,
                                                    unsigned long long* __restrict__ csr,
                                                    int E) {
    int e = blockIdx.x * 256 + threadIdx.x;
    if (e >= E) return;
    int d = dst[e];
    int pos = atomicAdd(&cur[d], 1);
    csr[pos] = ((unsigned long long)__float_as_uint(w[e]) << 32) | (unsigned)src[e];
}

// ---- aggregate: out[d] = bias + sum_{e in row d} w_e * h[src_e]  (no atomics) ----
// 32 lanes per dst row, each lane owns 4 consecutive cols.
__global__ __launch_bounds__(256) void agg_kernel(const unsigned short* __restrict__ H,
                                                  const int* __restrict__ rs,
                                                  const unsigned long long* __restrict__ csr,
                                                  const float* __restrict__ bias,
                                                  float* __restrict__ out, int M) {
    int row = blockIdx.x * 8 + (threadIdx.x >> 5);
    if (row >= M) return;
    int sub = threadIdx.x & 31;

    float4 acc = *reinterpret_cast<const float4*>(bias + sub * 4);
    int start = rs[row];
    int end = rs[row + 1];
    for (int j = start; j < end; j++) {
        unsigned long long p = csr[j];
        int s = (int)(p & 0xFFFFFFFFull);
        float wv = __uint_as_float((unsigned)(p >> 32));
        ushort4 v = *reinterpret_cast<const ushort4*>(H + (size_t)s * D_OUT + sub * 4);
        acc.x += wv * __uint_as_float((unsigned)v.x << 16);
        acc.y += wv * __uint_as_float((unsigned)v.y << 16);
        acc.z += wv * __uint_as_float((unsigned)v.z << 16);
        acc.w += wv * __uint_as_float((unsigned)v.w << 16);
    }
    *reinterpret_cast<float4*>(out + (size_t)row * D_OUT + sub * 4) = acc;
}

extern "C" void kernel_launch(void* const* d_in, const int* in_sizes, int n_in,
                              void* d_out, int out_size, void* d_ws, size_t ws_size,
                              hipStream_t stream) {
    const float* features    = (const float*)d_in[0];
    const int*   edge_src    = (const int*)d_in[1];
    const int*   edge_dst    = (const int*)d_in[2];
    const float* edge_weight = (const float*)d_in[3];
    const float* weights     = (const float*)d_in[4];
    const float* bias        = (const float*)d_in[5];
    float* out = (float*)d_out;

    const int M = in_sizes[0] / D_IN;   // 100000
    const int E = in_sizes[1];          // 640000

    char* ws = (char*)d_ws;
    unsigned short* hbf = (unsigned short*)(ws);                       // M*128 bf16
    unsigned short* Wt  = (unsigned short*)(ws + 25600000);            // 128*512 bf16
    int* deg            = (int*)(ws + 25731072);                       // M
    int* rs             = (int*)(ws + 26131072);                       // M+1
    int* cur            = (int*)(ws + 26531088);                       // M
    unsigned long long* csr = (unsigned long long*)(ws + 26931088);    // E
    int* bsum           = (int*)(ws + 32051088);                       // 128

    // 1) Wt = bf16(W^T)
    wt_kernel<<<256, 256, 0, stream>>>(weights, Wt);
    // 2) hbf = bf16(X @ W)  (MFMA)
    gemm_kernel<<<(M / 16 + 3) / 4, 256, 0, stream>>>(features, Wt, hbf, M);
    // 3) CSR build
    zero_kernel<<<(M + 255) / 256, 256, 0, stream>>>(deg, M);
    hist_kernel<<<(E + 255) / 256, 256, 0, stream>>>(edge_dst, deg, E);
    const int NB = (M + 1023) / 1024;   // 98 chunks
    scan1_kernel<<<NB, 256, 0, stream>>>(deg, rs, bsum, M);
    scan2_kernel<<<1, 128, 0, stream>>>(bsum, NB);
    scan3_kernel<<<(M + 255) / 256, 256, 0, stream>>>(rs, cur, bsum, M, E);
    build_kernel<<<(E + 255) / 256, 256, 0, stream>>>(edge_src, edge_dst, edge_weight,
                                                      cur, csr, E);
    // 4) gather-aggregate, bias fused, one store per output row
    agg_kernel<<<(M + 7) / 8, 256, 0, stream>>>(hbf, rs, csr, bias, out, M);
}

// Round 3
// 481.641 us; speedup vs baseline: 3.2283x; 1.0289x over previous
//
#include <hip/hip_runtime.h>

// GCN layer: out = segment_sum(edge_weight * (X@W)[edge_src], edge_dst) + bias
// Round 3: (a) GEMM software-pipelined: 2-deep register prefetch of X,
//              truncation-pack fp32->bf16 on the hot A path (v_perm)
//          (b) agg: 16 lanes/row, 2 edges in flight (2x MLP)
// ws layout (bytes):
//   hbf       [M*128 bf16]   @ 0          (25.6 MB)
//   Wt bf16   [128*512]      @ 25,600,000 (0.13 MB)  Wt[n][k]
//   deg  int  [M]            @ 25,731,072
//   rs   int  [M+1]          @ 26,131,072
//   cur  int  [M]            @ 26,531,088
//   csr  u64  [E]            @ 26,931,088 (5.12 MB)  (w_bits<<32 | src)
//   bsum int  [128]          @ 32,051,088

#define D_IN  512
#define D_OUT 128

typedef __attribute__((ext_vector_type(8))) short short8;
typedef __attribute__((ext_vector_type(4))) float f32x4;
typedef __attribute__((ext_vector_type(4))) int i32x4;
typedef __attribute__((ext_vector_type(8))) unsigned short u16x8;

static __device__ __forceinline__ unsigned short f2bf(float f) {
    unsigned u = __float_as_uint(f);
    unsigned r = (u + 0x7FFFu + ((u >> 16) & 1u)) >> 16;   // RNE
    return (unsigned short)r;
}

// pack two fp32 -> two bf16 (truncation; single v_perm-able op)
static __device__ __forceinline__ int pack2(float lo, float hi) {
    return (int)((__float_as_uint(hi) & 0xFFFF0000u) | (__float_as_uint(lo) >> 16));
}

// ---- Wt[n][k] = bf16(W[k][n]) ----
__global__ __launch_bounds__(256) void wt_kernel(const float* __restrict__ W,
                                                 unsigned short* __restrict__ Wt) {
    int t = blockIdx.x * 256 + threadIdx.x;      // 65536 threads
    int n = t >> 9;          // /512
    int k = t & 511;
    Wt[t] = f2bf(W[(size_t)k * D_OUT + n]);
}

// ---- GEMM: hbf[M,128] = bf16(X[M,512] @ W) via MFMA 16x16x32 bf16 ----
// One wave -> 16 rows x 128 cols. Block = 4 waves. No LDS.
// Fully-unrolled K loop (16 chunks of 32), 2-deep rotating prefetch.
__global__ __launch_bounds__(256) void gemm_kernel(const float* __restrict__ X,
                                                   const unsigned short* __restrict__ Wt,
                                                   unsigned short* __restrict__ H, int M) {
    const int lane = threadIdx.x & 63;
    const int wave_id = blockIdx.x * 4 + (threadIdx.x >> 6);
    const int row0 = wave_id * 16;
    if (row0 >= M) return;

    const int m = lane & 15;      // A row / B col within tile
    const int q = lane >> 4;      // quad: k = q*8 + j

    f32x4 acc[8];
#pragma unroll
    for (int t = 0; t < 8; t++) acc[t] = (f32x4){0.f, 0.f, 0.f, 0.f};

    const float* xrow = X + (size_t)(row0 + m) * D_IN + q * 8;
    const unsigned short* wrow = Wt + (size_t)m * D_IN + q * 8;

    float4 buf[3][2];
    buf[0][0] = *reinterpret_cast<const float4*>(xrow);
    buf[0][1] = *reinterpret_cast<const float4*>(xrow + 4);
    buf[1][0] = *reinterpret_cast<const float4*>(xrow + 32);
    buf[1][1] = *reinterpret_cast<const float4*>(xrow + 36);

#pragma unroll
    for (int i = 0; i < 16; i++) {
        if (i + 2 < 16) {
            buf[(i + 2) % 3][0] = *reinterpret_cast<const float4*>(xrow + (i + 2) * 32);
            buf[(i + 2) % 3][1] = *reinterpret_cast<const float4*>(xrow + (i + 2) * 32 + 4);
        }
        float4 u0 = buf[i % 3][0];
        float4 u1 = buf[i % 3][1];
        i32x4 ai;
        ai.x = pack2(u0.x, u0.y);
        ai.y = pack2(u0.z, u0.w);
        ai.z = pack2(u1.x, u1.y);
        ai.w = pack2(u1.z, u1.w);
        short8 a = __builtin_bit_cast(short8, ai);

        const unsigned short* wp = wrow + i * 32;
#pragma unroll
        for (int t = 0; t < 8; t++) {
            // B fragment: Wt[(t*16+m)][i*32 + q*8 + j]
            short8 b = *reinterpret_cast<const short8*>(wp + (size_t)t * 16 * D_IN);
            acc[t] = __builtin_amdgcn_mfma_f32_16x16x32_bf16(a, b, acc[t], 0, 0, 0);
        }
    }

    // C layout: col = lane&15, row = q*4 + r
#pragma unroll
    for (int t = 0; t < 8; t++) {
#pragma unroll
        for (int r = 0; r < 4; r++) {
            H[(size_t)(row0 + q * 4 + r) * D_OUT + t * 16 + m] = f2bf(acc[t][r]);
        }
    }
}

// ---- zero deg ----
__global__ __launch_bounds__(256) void zero_kernel(int* __restrict__ deg, int M) {
    int i = blockIdx.x * 256 + threadIdx.x;
    if (i < M) deg[i] = 0;
}

// ---- histogram of dst ----
__global__ __launch_bounds__(256) void hist_kernel(const int* __restrict__ dst,
                                                   int* __restrict__ deg, int E) {
    int e = blockIdx.x * 256 + threadIdx.x;
    if (e < E) atomicAdd(&deg[dst[e]], 1);
}

// ---- scan pass 1: per-1024-chunk local exclusive scan + chunk totals ----
__global__ __launch_bounds__(256) void scan1_kernel(const int* __restrict__ deg,
                                                    int* __restrict__ rs,
                                                    int* __restrict__ bsum, int M) {
    __shared__ int sdata[256];
    const int tid = threadIdx.x;
    const int base = blockIdx.x * 1024 + tid * 4;
    int v[4];
#pragma unroll
    for (int i = 0; i < 4; i++) v[i] = (base + i < M) ? deg[base + i] : 0;
    int tsum = v[0] + v[1] + v[2] + v[3];
    sdata[tid] = tsum;
    __syncthreads();
    for (int off = 1; off < 256; off <<= 1) {
        int add = (tid >= off) ? sdata[tid - off] : 0;
        __syncthreads();
        sdata[tid] += add;
        __syncthreads();
    }
    int excl = sdata[tid] - tsum;
#pragma unroll
    for (int i = 0; i < 4; i++) {
        if (base + i < M) rs[base + i] = excl;
        excl += v[i];
    }
    if (tid == 255) bsum[blockIdx.x] = sdata[255];
}

// ---- scan pass 2: exclusive scan of chunk totals (<=128 chunks) ----
__global__ __launch_bounds__(128) void scan2_kernel(int* __restrict__ bsum, int NB) {
    __shared__ int sdata[128];
    const int tid = threadIdx.x;
    int v = (tid < NB) ? bsum[tid] : 0;
    sdata[tid] = v;
    __syncthreads();
    for (int off = 1; off < 128; off <<= 1) {
        int add = (tid >= off) ? sdata[tid - off] : 0;
        __syncthreads();
        sdata[tid] += add;
        __syncthreads();
    }
    if (tid < NB) bsum[tid] = sdata[tid] - v;
}

// ---- scan pass 3: apply chunk offsets; fill cursor; set rs[M]=E ----
__global__ __launch_bounds__(256) void scan3_kernel(int* __restrict__ rs,
                                                    int* __restrict__ cur,
                                                    const int* __restrict__ bsum,
                                                    int M, int E) {
    int i = blockIdx.x * 256 + threadIdx.x;
    if (i < M) {
        int val = rs[i] + bsum[i >> 10];
        rs[i] = val;
        cur[i] = val;
    }
    if (i == 0) rs[M] = E;
}

// ---- build CSR: csr[pos] = (w_bits<<32) | src ----
__global__ __launch_bounds__(256) void build_kernel(const int* __restrict__ src,
                                                    const int* __restrict__ dst,
                                                    const float* __restrict__ w,
                                                    int* __restrict__ cur,
                                                    unsigned long long* __restrict__ csr,
                                                    int E) {
    int e = blockIdx.x * 256 + threadIdx.x;
    if (e >= E) return;
    int d = dst[e];
    int pos = atomicAdd(&cur[d], 1);
    csr[pos] = ((unsigned long long)__float_as_uint(w[e]) << 32) | (unsigned)src[e];
}

// ---- aggregate: out[d] = bias + sum_{e in row d} w_e * h[src_e]  (no atomics) ----
// 16 lanes per dst row; each lane owns 8 cols (one 16B bf16 gather per edge).
// Edge loop unrolled x2: two independent gathers in flight.
__global__ __launch_bounds__(256) void agg_kernel(const unsigned short* __restrict__ H,
                                                  const int* __restrict__ rs,
                                                  const unsigned long long* __restrict__ csr,
                                                  const float* __restrict__ bias,
                                                  float* __restrict__ out, int M) {
    int row = blockIdx.x * 16 + (threadIdx.x >> 4);
    if (row >= M) return;
    int sub = threadIdx.x & 15;    // cols [sub*8, sub*8+8)

    float acc[8];
#pragma unroll
    for (int c = 0; c < 8; c++) acc[c] = bias[sub * 8 + c];

    int j = rs[row];
    int end = rs[row + 1];

    for (; j + 2 <= end; j += 2) {
        unsigned long long p0 = csr[j];
        unsigned long long p1 = csr[j + 1];
        int s0 = (int)(p0 & 0xFFFFFFFFull);
        int s1 = (int)(p1 & 0xFFFFFFFFull);
        float w0 = __uint_as_float((unsigned)(p0 >> 32));
        float w1 = __uint_as_float((unsigned)(p1 >> 32));
        u16x8 v0 = *reinterpret_cast<const u16x8*>(H + (size_t)s0 * D_OUT + sub * 8);
        u16x8 v1 = *reinterpret_cast<const u16x8*>(H + (size_t)s1 * D_OUT + sub * 8);
#pragma unroll
        for (int c = 0; c < 8; c++) {
            acc[c] += w0 * __uint_as_float((unsigned)v0[c] << 16);
            acc[c] += w1 * __uint_as_float((unsigned)v1[c] << 16);
        }
    }
    if (j < end) {
        unsigned long long p0 = csr[j];
        int s0 = (int)(p0 & 0xFFFFFFFFull);
        float w0 = __uint_as_float((unsigned)(p0 >> 32));
        u16x8 v0 = *reinterpret_cast<const u16x8*>(H + (size_t)s0 * D_OUT + sub * 8);
#pragma unroll
        for (int c = 0; c < 8; c++)
            acc[c] += w0 * __uint_as_float((unsigned)v0[c] << 16);
    }

    float4 o0 = make_float4(acc[0], acc[1], acc[2], acc[3]);
    float4 o1 = make_float4(acc[4], acc[5], acc[6], acc[7]);
    *reinterpret_cast<float4*>(out + (size_t)row * D_OUT + sub * 8) = o0;
    *reinterpret_cast<float4*>(out + (size_t)row * D_OUT + sub * 8 + 4) = o1;
}

extern "C" void kernel_launch(void* const* d_in, const int* in_sizes, int n_in,
                              void* d_out, int out_size, void* d_ws, size_t ws_size,
                              hipStream_t stream) {
    const float* features    = (const float*)d_in[0];
    const int*   edge_src    = (const int*)d_in[1];
    const int*   edge_dst    = (const int*)d_in[2];
    const float* edge_weight = (const float*)d_in[3];
    const float* weights     = (const float*)d_in[4];
    const float* bias        = (const float*)d_in[5];
    float* out = (float*)d_out;

    const int M = in_sizes[0] / D_IN;   // 100000
    const int E = in_sizes[1];          // 640000

    char* ws = (char*)d_ws;
    unsigned short* hbf = (unsigned short*)(ws);                       // M*128 bf16
    unsigned short* Wt  = (unsigned short*)(ws + 25600000);            // 128*512 bf16
    int* deg            = (int*)(ws + 25731072);                       // M
    int* rs             = (int*)(ws + 26131072);                       // M+1
    int* cur            = (int*)(ws + 26531088);                       // M
    unsigned long long* csr = (unsigned long long*)(ws + 26931088);    // E
    int* bsum           = (int*)(ws + 32051088);                       // 128

    // 1) Wt = bf16(W^T)
    wt_kernel<<<256, 256, 0, stream>>>(weights, Wt);
    // 2) hbf = bf16(X @ W)  (MFMA, pipelined)
    gemm_kernel<<<(M / 16 + 3) / 4, 256, 0, stream>>>(features, Wt, hbf, M);
    // 3) CSR build
    zero_kernel<<<(M + 255) / 256, 256, 0, stream>>>(deg, M);
    hist_kernel<<<(E + 255) / 256, 256, 0, stream>>>(edge_dst, deg, E);
    const int NB = (M + 1023) / 1024;   // 98 chunks
    scan1_kernel<<<NB, 256, 0, stream>>>(deg, rs, bsum, M);
    scan2_kernel<<<1, 128, 0, stream>>>(bsum, NB);
    scan3_kernel<<<(M + 255) / 256, 256, 0, stream>>>(rs, cur, bsum, M, E);
    build_kernel<<<(E + 255) / 256, 256, 0, stream>>>(edge_src, edge_dst, edge_weight,
                                                      cur, csr, E);
    // 4) gather-aggregate, bias fused, one store per output row
    agg_kernel<<<(M + 15) / 16, 256, 0, stream>>>(hbf, rs, csr, bias, out, M);
}

// Round 4
// 415.418 us; speedup vs baseline: 3.7430x; 1.1594x over previous
//
#include <hip/hip_runtime.h>

// GCN layer: out = segment_sum(edge_weight * (X@W)[edge_src], edge_dst) + bias
// Round 4: m97-style GEMM — 128x128 block tile, BK=64, global_load_lds(16B)
//          staging with XOR-swizzled LDS layout (conflict-free reads),
//          2x2 wave grid, 4x4 MFMA tiles/wave. agg unrolled x4.
// ws layout (bytes):
//   hbf       [M*128 bf16]   @ 0          (25.6 MB)
//   Wt bf16   [128*512]      @ 25,600,000 (0.13 MB)  Wt[n][k]
//   deg  int  [M]            @ 25,731,072
//   rs   int  [M+1]          @ 26,131,072
//   cur  int  [M]            @ 26,531,088
//   csr  u64  [E]            @ 26,931,088 (5.12 MB)  (w_bits<<32 | src)
//   bsum int  [128]          @ 32,051,088

#define D_IN  512
#define D_OUT 128

typedef __attribute__((ext_vector_type(8))) short short8;
typedef __attribute__((ext_vector_type(4))) float f32x4;
typedef __attribute__((ext_vector_type(4))) int i32x4;
typedef __attribute__((ext_vector_type(8))) unsigned short u16x8;

typedef __attribute__((address_space(1))) const unsigned int glob_u32;
typedef __attribute__((address_space(3))) unsigned int lds_u32;

static __device__ __forceinline__ unsigned short f2bf(float f) {
    unsigned u = __float_as_uint(f);
    unsigned r = (u + 0x7FFFu + ((u >> 16) & 1u)) >> 16;   // RNE
    return (unsigned short)r;
}

// pack two fp32 -> two bf16 (truncation; v_perm)
static __device__ __forceinline__ int pack2(float lo, float hi) {
    return (int)((__float_as_uint(hi) & 0xFFFF0000u) | (__float_as_uint(lo) >> 16));
}

// ---- prep: Wt[n][k] = bf16(W[k][n]);  deg = 0 ----
__global__ __launch_bounds__(256) void prep_kernel(const float* __restrict__ W,
                                                   unsigned short* __restrict__ Wt,
                                                   int* __restrict__ deg, int M) {
    int t = blockIdx.x * 256 + threadIdx.x;
    if (t < D_OUT * D_IN) {
        int n = t >> 9;
        int k = t & 511;
        Wt[t] = f2bf(W[(size_t)k * D_OUT + n]);
    }
    if (t < M) deg[t] = 0;
}

// ---- GEMM: hbf[M,128] = bf16(X[M,512] @ W), MFMA 16x16x32 bf16 ----
// Block: 256 thr / 4 waves, tile 128 rows x 128 cols, BK=64.
// A staged fp32 (32KB), B staged bf16 (16KB) via global_load_lds 16B,
// XOR-swizzled slots so fragment reads are bank-conflict-free.
__global__ __launch_bounds__(256, 3) void gemm_kernel(const float* __restrict__ X,
                                                      const unsigned short* __restrict__ Wt,
                                                      unsigned short* __restrict__ H, int M) {
    __shared__ float As[128 * 64];            // slot s (16B) = row*16 + (kq ^ (row&15))
    __shared__ unsigned short Bs[128 * 64];   // slot s (16B) = n*8 + (kq8 ^ (n&7))

    const int tid = threadIdx.x;
    const int lane = tid & 63;
    const int w = tid >> 6;
    const int block_row = blockIdx.x * 128;

    const int m = lane & 15;
    const int q = lane >> 4;
    const int wave_row = (w >> 1) * 64;
    const int wave_col = (w & 1) * 64;

    f32x4 acc[4][4];
#pragma unroll
    for (int a = 0; a < 4; a++)
#pragma unroll
        for (int b = 0; b < 4; b++) acc[a][b] = (f32x4){0.f, 0.f, 0.f, 0.f};

    for (int kc = 0; kc < D_IN; kc += 64) {
        // ---- stage A: 2048 slots, 8 instrs/wave ----
#pragma unroll
        for (int it = 0; it < 8; it++) {
            int slot_base = w * 512 + it * 64;          // wave-uniform
            int s = slot_base + lane;
            int row = s >> 4;
            int kq = (s & 15) ^ (row & 15);
            int grow = block_row + row;
            if (grow >= M) grow = M - 1;                 // clamp (tail block)
            const float* gp = X + (size_t)grow * D_IN + kc + kq * 4;
            __builtin_amdgcn_global_load_lds((glob_u32*)gp,
                                             (lds_u32*)(As + (size_t)slot_base * 4),
                                             16, 0, 0);
        }
        // ---- stage B: 1024 slots, 4 instrs/wave ----
#pragma unroll
        for (int it = 0; it < 4; it++) {
            int slot_base = w * 256 + it * 64;
            int s = slot_base + lane;
            int n = s >> 3;
            int kq8 = (s & 7) ^ (n & 7);
            const unsigned short* gp = Wt + (size_t)n * D_IN + kc + kq8 * 8;
            __builtin_amdgcn_global_load_lds((glob_u32*)gp,
                                             (lds_u32*)(Bs + (size_t)slot_base * 8),
                                             16, 0, 0);
        }
        __syncthreads();

        // ---- compute: 2 ksubs x 16 MFMAs ----
#pragma unroll
        for (int ks = 0; ks < 2; ks++) {
            const int ksub = ks * 32;
            short8 afr[4];
#pragma unroll
            for (int rg = 0; rg < 4; rg++) {
                int row = wave_row + rg * 16 + m;
                int kq0 = (ksub >> 2) + 2 * q;
                float4 u0 = *reinterpret_cast<const float4*>(
                    As + (size_t)(row * 16 + (kq0 ^ (row & 15))) * 4);
                float4 u1 = *reinterpret_cast<const float4*>(
                    As + (size_t)(row * 16 + ((kq0 + 1) ^ (row & 15))) * 4);
                i32x4 ai;
                ai.x = pack2(u0.x, u0.y);
                ai.y = pack2(u0.z, u0.w);
                ai.z = pack2(u1.x, u1.y);
                ai.w = pack2(u1.z, u1.w);
                afr[rg] = __builtin_bit_cast(short8, ai);
            }
            short8 bfr[4];
#pragma unroll
            for (int cg = 0; cg < 4; cg++) {
                int n = wave_col + cg * 16 + m;
                int kq8 = (ksub >> 3) + q;
                bfr[cg] = *reinterpret_cast<const short8*>(
                    Bs + (size_t)(n * 8 + (kq8 ^ (n & 7))) * 8);
            }
#pragma unroll
            for (int rg = 0; rg < 4; rg++)
#pragma unroll
                for (int cg = 0; cg < 4; cg++)
                    acc[rg][cg] = __builtin_amdgcn_mfma_f32_16x16x32_bf16(
                        afr[rg], bfr[cg], acc[rg][cg], 0, 0, 0);
        }
        __syncthreads();
    }

    // ---- epilogue: C layout col = m, row = q*4 + r ----
#pragma unroll
    for (int rg = 0; rg < 4; rg++) {
#pragma unroll
        for (int r = 0; r < 4; r++) {
            int grow = block_row + wave_row + rg * 16 + q * 4 + r;
            if (grow < M) {
#pragma unroll
                for (int cg = 0; cg < 4; cg++)
                    H[(size_t)grow * D_OUT + wave_col + cg * 16 + m] = f2bf(acc[rg][cg][r]);
            }
        }
    }
}

// ---- histogram of dst ----
__global__ __launch_bounds__(256) void hist_kernel(const int* __restrict__ dst,
                                                   int* __restrict__ deg, int E) {
    int e = blockIdx.x * 256 + threadIdx.x;
    if (e < E) atomicAdd(&deg[dst[e]], 1);
}

// ---- scan pass 1: per-1024-chunk local exclusive scan + chunk totals ----
__global__ __launch_bounds__(256) void scan1_kernel(const int* __restrict__ deg,
                                                    int* __restrict__ rs,
                                                    int* __restrict__ bsum, int M) {
    __shared__ int sdata[256];
    const int tid = threadIdx.x;
    const int base = blockIdx.x * 1024 + tid * 4;
    int v[4];
#pragma unroll
    for (int i = 0; i < 4; i++) v[i] = (base + i < M) ? deg[base + i] : 0;
    int tsum = v[0] + v[1] + v[2] + v[3];
    sdata[tid] = tsum;
    __syncthreads();
    for (int off = 1; off < 256; off <<= 1) {
        int add = (tid >= off) ? sdata[tid - off] : 0;
        __syncthreads();
        sdata[tid] += add;
        __syncthreads();
    }
    int excl = sdata[tid] - tsum;
#pragma unroll
    for (int i = 0; i < 4; i++) {
        if (base + i < M) rs[base + i] = excl;
        excl += v[i];
    }
    if (tid == 255) bsum[blockIdx.x] = sdata[255];
}

// ---- scan pass 2: exclusive scan of chunk totals (<=128 chunks) ----
__global__ __launch_bounds__(128) void scan2_kernel(int* __restrict__ bsum, int NB) {
    __shared__ int sdata[128];
    const int tid = threadIdx.x;
    int v = (tid < NB) ? bsum[tid] : 0;
    sdata[tid] = v;
    __syncthreads();
    for (int off = 1; off < 128; off <<= 1) {
        int add = (tid >= off) ? sdata[tid - off] : 0;
        __syncthreads();
        sdata[tid] += add;
        __syncthreads();
    }
    if (tid < NB) bsum[tid] = sdata[tid] - v;
}

// ---- scan pass 3: apply chunk offsets; fill cursor; set rs[M]=E ----
__global__ __launch_bounds__(256) void scan3_kernel(int* __restrict__ rs,
                                                    int* __restrict__ cur,
                                                    const int* __restrict__ bsum,
                                                    int M, int E) {
    int i = blockIdx.x * 256 + threadIdx.x;
    if (i < M) {
        int val = rs[i] + bsum[i >> 10];
        rs[i] = val;
        cur[i] = val;
    }
    if (i == 0) rs[M] = E;
}

// ---- build CSR: csr[pos] = (w_bits<<32) | src ----
__global__ __launch_bounds__(256) void build_kernel(const int* __restrict__ src,
                                                    const int* __restrict__ dst,
                                                    const float* __restrict__ w,
                                                    int* __restrict__ cur,
                                                    unsigned long long* __restrict__ csr,
                                                    int E) {
    int e = blockIdx.x * 256 + threadIdx.x;
    if (e >= E) return;
    int d = dst[e];
    int pos = atomicAdd(&cur[d], 1);
    csr[pos] = ((unsigned long long)__float_as_uint(w[e]) << 32) | (unsigned)src[e];
}

// ---- aggregate: out[d] = bias + sum_{e in row d} w_e * h[src_e]  (no atomics) ----
// 16 lanes per dst row; each lane owns 8 cols (one 16B bf16 gather per edge).
// Edge loop unrolled x4: four independent gathers in flight.
__global__ __launch_bounds__(256) void agg_kernel(const unsigned short* __restrict__ H,
                                                  const int* __restrict__ rs,
                                                  const unsigned long long* __restrict__ csr,
                                                  const float* __restrict__ bias,
                                                  float* __restrict__ out, int M) {
    int row = blockIdx.x * 16 + (threadIdx.x >> 4);
    if (row >= M) return;
    int sub = threadIdx.x & 15;    // cols [sub*8, sub*8+8)

    float acc[8];
#pragma unroll
    for (int c = 0; c < 8; c++) acc[c] = bias[sub * 8 + c];

    int j = rs[row];
    int end = rs[row + 1];

    for (; j + 4 <= end; j += 4) {
        unsigned long long p0 = csr[j];
        unsigned long long p1 = csr[j + 1];
        unsigned long long p2 = csr[j + 2];
        unsigned long long p3 = csr[j + 3];
        u16x8 v0 = *reinterpret_cast<const u16x8*>(
            H + (size_t)(unsigned)(p0 & 0xFFFFFFFFull) * D_OUT + sub * 8);
        u16x8 v1 = *reinterpret_cast<const u16x8*>(
            H + (size_t)(unsigned)(p1 & 0xFFFFFFFFull) * D_OUT + sub * 8);
        u16x8 v2 = *reinterpret_cast<const u16x8*>(
            H + (size_t)(unsigned)(p2 & 0xFFFFFFFFull) * D_OUT + sub * 8);
        u16x8 v3 = *reinterpret_cast<const u16x8*>(
            H + (size_t)(unsigned)(p3 & 0xFFFFFFFFull) * D_OUT + sub * 8);
        float w0 = __uint_as_float((unsigned)(p0 >> 32));
        float w1 = __uint_as_float((unsigned)(p1 >> 32));
        float w2 = __uint_as_float((unsigned)(p2 >> 32));
        float w3 = __uint_as_float((unsigned)(p3 >> 32));
#pragma unroll
        for (int c = 0; c < 8; c++) {
            acc[c] += w0 * __uint_as_float((unsigned)v0[c] << 16);
            acc[c] += w1 * __uint_as_float((unsigned)v1[c] << 16);
            acc[c] += w2 * __uint_as_float((unsigned)v2[c] << 16);
            acc[c] += w3 * __uint_as_float((unsigned)v3[c] << 16);
        }
    }
    for (; j < end; j++) {
        unsigned long long p0 = csr[j];
        float w0 = __uint_as_float((unsigned)(p0 >> 32));
        u16x8 v0 = *reinterpret_cast<const u16x8*>(
            H + (size_t)(unsigned)(p0 & 0xFFFFFFFFull) * D_OUT + sub * 8);
#pragma unroll
        for (int c = 0; c < 8; c++)
            acc[c] += w0 * __uint_as_float((unsigned)v0[c] << 16);
    }

    float4 o0 = make_float4(acc[0], acc[1], acc[2], acc[3]);
    float4 o1 = make_float4(acc[4], acc[5], acc[6], acc[7]);
    *reinterpret_cast<float4*>(out + (size_t)row * D_OUT + sub * 8) = o0;
    *reinterpret_cast<float4*>(out + (size_t)row * D_OUT + sub * 8 + 4) = o1;
}

extern "C" void kernel_launch(void* const* d_in, const int* in_sizes, int n_in,
                              void* d_out, int out_size, void* d_ws, size_t ws_size,
                              hipStream_t stream) {
    const float* features    = (const float*)d_in[0];
    const int*   edge_src    = (const int*)d_in[1];
    const int*   edge_dst    = (const int*)d_in[2];
    const float* edge_weight = (const float*)d_in[3];
    const float* weights     = (const float*)d_in[4];
    const float* bias        = (const float*)d_in[5];
    float* out = (float*)d_out;

    const int M = in_sizes[0] / D_IN;   // 100000
    const int E = in_sizes[1];          // 640000

    char* ws = (char*)d_ws;
    unsigned short* hbf = (unsigned short*)(ws);                       // M*128 bf16
    unsigned short* Wt  = (unsigned short*)(ws + 25600000);            // 128*512 bf16
    int* deg            = (int*)(ws + 25731072);                       // M
    int* rs             = (int*)(ws + 26131072);                       // M+1
    int* cur            = (int*)(ws + 26531088);                       // M
    unsigned long long* csr = (unsigned long long*)(ws + 26931088);    // E
    int* bsum           = (int*)(ws + 32051088);                       // 128

    // 1) Wt = bf16(W^T); deg = 0
    prep_kernel<<<(M + 255) / 256, 256, 0, stream>>>(weights, Wt, deg, M);
    // 2) hbf = bf16(X @ W)  (MFMA, LDS-staged)
    gemm_kernel<<<(M + 127) / 128, 256, 0, stream>>>(features, Wt, hbf, M);
    // 3) CSR build
    hist_kernel<<<(E + 255) / 256, 256, 0, stream>>>(edge_dst, deg, E);
    const int NB = (M + 1023) / 1024;   // 98 chunks
    scan1_kernel<<<NB, 256, 0, stream>>>(deg, rs, bsum, M);
    scan2_kernel<<<1, 128, 0, stream>>>(bsum, NB);
    scan3_kernel<<<(M + 255) / 256, 256, 0, stream>>>(rs, cur, bsum, M, E);
    build_kernel<<<(E + 255) / 256, 256, 0, stream>>>(edge_src, edge_dst, edge_weight,
                                                      cur, csr, E);
    // 4) gather-aggregate, bias fused, one store per output row
    agg_kernel<<<(M + 15) / 16, 256, 0, stream>>>(hbf, rs, csr, bias, out, M);
}